// Round 1
// baseline (346.084 us; speedup 1.0000x reference)
//
#include <hip/hip_runtime.h>
#include <math.h>

#define S_LEN 4096
#define B_SZ  64
#define D_SZ  64
#define N_SZ  128
#define L_SZ  2
#define NSIG  32000
#define CH    8

// f32-rounded constants matching jnp.float32(...)
#define PHI_F     1.6180339887498949f
#define TWO_PI_F  6.2831853071795862f

// ---------------------------------------------------------------------------
// Phase 1: the sequential scan.  grid = B (64 blocks), block = D (64 lanes).
// Each lane owns one (b,d) chain.  hr' = cos(th_r+th_i), hi' = sin(th_r+th_i),
// psi = (hr+hi)/lambda + 2*(b_t + wrap(t*phi)).
// Token ids + tau table staged in LDS; emb gathers double-buffered in regs.
// ---------------------------------------------------------------------------
__global__ __launch_bounds__(64) void scan_kernel(
    const int*   __restrict__ ids,
    const float* __restrict__ emb,
    float2*      __restrict__ xf)     // [b][d] final h
{
    __shared__ int   s_ids[S_LEN];
    __shared__ float s_tau[S_LEN];

    const int b = blockIdx.x;
    const int d = threadIdx.x;

    for (int i = d; i < S_LEN; i += 64) {
        s_ids[i] = ids[b * S_LEN + i];
        s_tau[i] = fmodf((float)i * PHI_F, TWO_PI_F);
    }
    __syncthreads();

    float hr = 0.0f, hi = 0.0f;
    float wA[CH], bA[CH], wB[CH], bB[CH];

    // prologue: chunk 0 -> A
    #pragma unroll
    for (int j = 0; j < CH; ++j) {
        int idx = s_ids[j];
        wA[j] = emb[idx * 128 + d];
        bA[j] = emb[idx * 128 + 64 + d];
    }

    const int NCHUNK = S_LEN / CH;   // 512
    for (int c = 0; c < NCHUNK; c += 2) {
        // prefetch chunk c+1 -> B
        {
            int base = (c + 1 < NCHUNK) ? (c + 1) * CH : 0;
            #pragma unroll
            for (int j = 0; j < CH; ++j) {
                int idx = s_ids[base + j];
                wB[j] = emb[idx * 128 + d];
                bB[j] = emb[idx * 128 + 64 + d];
            }
        }
        // compute chunk c from A
        #pragma unroll
        for (int j = 0; j < CH; ++j) {
            int   t    = c * CH + j;
            float invl = 1.0f / (1.0f + fabsf(wA[j]));
            float bs2  = 2.0f * (bA[j] + s_tau[t]);
            float psi  = (hr + hi) * invl + bs2;
            hr = __cosf(psi);
            hi = __sinf(psi);
        }
        // prefetch chunk c+2 -> A
        {
            int base = (c + 2 < NCHUNK) ? (c + 2) * CH : 0;
            #pragma unroll
            for (int j = 0; j < CH; ++j) {
                int idx = s_ids[base + j];
                wA[j] = emb[idx * 128 + d];
                bA[j] = emb[idx * 128 + 64 + d];
            }
        }
        // compute chunk c+1 from B
        #pragma unroll
        for (int j = 0; j < CH; ++j) {
            int   t    = (c + 1) * CH + j;
            float invl = 1.0f / (1.0f + fabsf(wB[j]));
            float bs2  = 2.0f * (bB[j] + s_tau[t]);
            float psi  = (hr + hi) * invl + bs2;
            hr = __cosf(psi);
            hi = __sinf(psi);
        }
    }

    xf[b * 64 + d] = make_float2(hr, hi);
}

// ---------------------------------------------------------------------------
// Phase 2: the two resonant layers at t_last = (S-1)*phi.
// grid = B (64 blocks), block = N (128 threads).
// ---------------------------------------------------------------------------
__global__ __launch_bounds__(128) void layers_kernel(
    const float2* __restrict__ xf,       // [b][d]
    const float*  __restrict__ win_r,    // [L][D][N]
    const float*  __restrict__ win_i,
    const float*  __restrict__ wout_r,   // [L][N][D]
    const float*  __restrict__ wout_i,
    const float*  __restrict__ lw,       // [L][N]
    const float*  __restrict__ lb,
    float2*       __restrict__ xft)      // [d][b] for the projection kernel
{
    const int b = blockIdx.x;
    const int n = threadIdx.x;

    __shared__ float s_xr[D_SZ], s_xi[D_SZ];
    __shared__ float s_vr[N_SZ], s_vi[N_SZ];

    if (n < D_SZ) {
        float2 v = xf[b * D_SZ + n];
        s_xr[n] = v.x;
        s_xi[n] = v.y;
    }
    __syncthreads();

    const float t_last = (float)(4095.0 * 1.618033988749895);
    const float t_wrap = fmodf(t_last, TWO_PI_F);

    for (int l = 0; l < L_SZ; ++l) {
        // u = complex_linear(x, win)
        float ur = 0.0f, ui = 0.0f;
        const float* wr = win_r + l * D_SZ * N_SZ;
        const float* wi = win_i + l * D_SZ * N_SZ;
        for (int dd = 0; dd < D_SZ; ++dd) {
            float xr = s_xr[dd], xi = s_xi[dd];
            float ar = wr[dd * N_SZ + n], ai = wi[dd * N_SZ + n];
            ur = fmaf(xr, ar, fmaf(-xi, ai, ur));
            ui = fmaf(xr, ai, fmaf( xi, ar, ui));
        }
        // rotate + swish
        float lam = 1.0f + fabsf(lw[l * N_SZ + n]);
        float th  = t_wrap / lam + lb[l * N_SZ + n];
        float sn  = sinf(th), cs = cosf(th);
        float vr  = ur * cs - ui * sn;
        float vi  = ur * sn + ui * cs;
        vr = vr / (1.0f + expf(-vr));
        vi = vi / (1.0f + expf(-vi));
        s_vr[n] = vr;
        s_vi[n] = vi;
        __syncthreads();

        // y = complex_linear(v, wout)
        float yr = 0.0f, yi = 0.0f;
        if (n < D_SZ) {
            const float* orp = wout_r + l * N_SZ * D_SZ;
            const float* oip = wout_i + l * N_SZ * D_SZ;
            for (int j = 0; j < N_SZ; ++j) {
                float vr2 = s_vr[j], vi2 = s_vi[j];
                float br = orp[j * D_SZ + n], bi = oip[j * D_SZ + n];
                yr = fmaf(vr2, br, fmaf(-vi2, bi, yr));
                yi = fmaf(vr2, bi, fmaf( vi2, br, yi));
            }
        }
        __syncthreads();
        if (n < D_SZ) {
            s_xr[n] = yr;
            s_xi[n] = yi;
        }
        __syncthreads();
    }

    if (n < D_SZ) {
        xft[n * B_SZ + b] = make_float2(s_xr[n], s_xi[n]);
    }
}

// ---------------------------------------------------------------------------
// Phase 3: out[b][v] = xr[b]@(wr+wi)[:,v] + xi[b]@(wr-wi)[:,v].
// grid = NSIG/16 blocks x 64 lanes (lane = b).  Weight addresses are
// wave-uniform (blockIdx + loop counters) -> scalar loads; x is tiny and
// L1-resident.
// ---------------------------------------------------------------------------
#define VCH 16
__global__ __launch_bounds__(64) void proj_kernel(
    const float2* __restrict__ xft,    // [d][b]
    const float*  __restrict__ owr,    // [D][NSIG]
    const float*  __restrict__ owi,
    float*        __restrict__ out)    // [B][NSIG]
{
    const int v0   = blockIdx.x * VCH;
    const int lane = threadIdx.x;      // = b

    float acc[VCH];
    #pragma unroll
    for (int k = 0; k < VCH; ++k) acc[k] = 0.0f;

    for (int dd = 0; dd < D_SZ; ++dd) {
        float2 x = xft[dd * B_SZ + lane];
        #pragma unroll
        for (int k = 0; k < VCH; ++k) {
            float a = owr[dd * NSIG + v0 + k];
            float c = owi[dd * NSIG + v0 + k];
            acc[k] = fmaf(x.x, a + c, fmaf(x.y, a - c, acc[k]));
        }
    }

    float4* o4 = (float4*)(out + (size_t)lane * NSIG + v0);
    #pragma unroll
    for (int k = 0; k < VCH / 4; ++k) {
        o4[k] = make_float4(acc[4 * k], acc[4 * k + 1],
                            acc[4 * k + 2], acc[4 * k + 3]);
    }
}

// ---------------------------------------------------------------------------
extern "C" void kernel_launch(void* const* d_in, const int* in_sizes, int n_in,
                              void* d_out, int out_size, void* d_ws, size_t ws_size,
                              hipStream_t stream)
{
    const int*   ids    = (const int*)  d_in[0];
    const float* emb    = (const float*)d_in[1];
    const float* win_r  = (const float*)d_in[2];
    const float* win_i  = (const float*)d_in[3];
    const float* wout_r = (const float*)d_in[4];
    const float* wout_i = (const float*)d_in[5];
    const float* lw     = (const float*)d_in[6];
    const float* lb     = (const float*)d_in[7];
    const float* owr    = (const float*)d_in[8];
    const float* owi    = (const float*)d_in[9];
    float*       out    = (float*)d_out;

    float2* xf  = (float2*)d_ws;                        // 4096 float2 = 32 KB
    float2* xft = (float2*)((char*)d_ws + 32 * 1024);   // 4096 float2 = 32 KB

    scan_kernel<<<B_SZ, 64, 0, stream>>>(ids, emb, xf);
    layers_kernel<<<B_SZ, 128, 0, stream>>>(xf, win_r, win_i, wout_r, wout_i,
                                            lw, lb, xft);
    proj_kernel<<<NSIG / VCH, 64, 0, stream>>>(xft, owr, owi, out);
}

// Round 2
// 189.619 us; speedup vs baseline: 1.8252x; 1.8252x over previous
//
#include <hip/hip_runtime.h>
#include <math.h>

#define S_LEN 4096
#define B_SZ  64
#define D_SZ  64
#define N_SZ  128
#define L_SZ  2
#define NSIG  32000
#define CH    8
#define NCHUNK (S_LEN / CH)   // 512

// f32-rounded constants matching jnp.float32(...)
#define PHI_F     1.6180339887498949f
#define TWO_PI_F  6.2831853071795862f
#define INV_PI_F  0.31830988618379067f
#define SQ2_I2PI  0.22507907903927651f   // sqrt(2)/(2*pi)

// ---------------------------------------------------------------------------
// Pre-pass: transform emb table so the scan's inner loop is 1 load + 1 add +
// fma + v_sin.  embT[v*64+d] = ( sqrt2/(2pi*(1+|w|)),  b/pi ).
// ---------------------------------------------------------------------------
__global__ __launch_bounds__(256) void transform_kernel(
    const float* __restrict__ emb, float2* __restrict__ embT)
{
    int e = blockIdx.x * 256 + threadIdx.x;   // [0, 32000*64)
    int v = e >> 6, d = e & 63;
    float w = emb[(v << 7) + d];
    float b = emb[(v << 7) + 64 + d];
    embT[e] = make_float2(SQ2_I2PI * __builtin_amdgcn_rcpf(1.0f + fabsf(w)),
                          b * INV_PI_F);
}

// ---------------------------------------------------------------------------
// Phase 1: the sequential scan.  grid = B (64 blocks), block = D (64 lanes).
// Identity: hr' = cos(psi), hi' = sin(psi), psi = (hr+hi)/lam + 2(b+tau).
// Track u = (hr+hi)/sqrt2:  q = fma(u, sqrt2/(2pi lam), (b+tau)/pi + 1/8);
//                           u = sin(2pi q).
// Dependent chain per step: fma -> v_sin.  8-slot register ring prefetches
// 7 chunks (56 steps, 56 outstanding loads) ahead.
// ---------------------------------------------------------------------------
template<bool XF>
__global__ __launch_bounds__(64) void scan_kernel(
    const int*    __restrict__ ids,
    const float*  __restrict__ embR,    // raw emb        (used when !XF)
    const float2* __restrict__ embT,    // transformed    (used when XF)
    float2*       __restrict__ xf)      // [b][d] final (hr,hi)
{
    __shared__ int   s_ids[S_LEN];
    __shared__ float s_t2[S_LEN];       // tau/pi + 0.125

    const int b = blockIdx.x;
    const int d = threadIdx.x;

    for (int i = d; i < S_LEN; i += 64) {
        s_ids[i] = ids[b * S_LEN + i];
        s_t2[i]  = fmodf((float)i * PHI_F, TWO_PI_F) * INV_PI_F + 0.125f;
    }
    __syncthreads();

    float2 q0[CH], q1[CH], q2[CH], q3[CH], q4[CH], q5[CH], q6[CH], q7[CH];
    float  u = 0.0f, qang = 0.0f;

#define CLMP(X) ((X) < NCHUNK ? (X) : 0)

#define ISSUE(BUF, CHUNK) do {                                              \
    int base_ = (CHUNK) * CH;                                               \
    _Pragma("unroll")                                                       \
    for (int j = 0; j < CH; ++j) {                                          \
        int idx_ = s_ids[base_ + j];                                        \
        if constexpr (XF) {                                                 \
            BUF[j] = embT[idx_ * 64 + d];                                   \
        } else {                                                            \
            BUF[j].x = embR[idx_ * 128 + d];                                \
            BUF[j].y = embR[idx_ * 128 + 64 + d];                           \
        }                                                                   \
    }                                                                       \
} while (0)

#define CHAIN(BUF, CHUNK) do {                                              \
    int base_ = (CHUNK) * CH;                                               \
    _Pragma("unroll")                                                       \
    for (int j = 0; j < CH; ++j) {                                          \
        float t2_ = s_t2[base_ + j];                                        \
        float A_, C_;                                                       \
        if constexpr (XF) {                                                 \
            A_ = BUF[j].x;                                                  \
            C_ = BUF[j].y + t2_;                                            \
        } else {                                                            \
            A_ = SQ2_I2PI * __builtin_amdgcn_rcpf(1.0f + fabsf(BUF[j].x));  \
            C_ = fmaf(BUF[j].y, INV_PI_F, t2_);                             \
        }                                                                   \
        qang = fmaf(u, A_, C_);                                             \
        u    = __builtin_amdgcn_sinf(qang);                                 \
    }                                                                       \
} while (0)

    // prologue: chunks 0..6 into slots 0..6
    ISSUE(q0, 0); ISSUE(q1, 1); ISSUE(q2, 2); ISSUE(q3, 3);
    ISSUE(q4, 4); ISSUE(q5, 5); ISSUE(q6, 6);

    for (int c = 0; c < NCHUNK; c += 8) {
        ISSUE(q7, CLMP(c + 7));  CHAIN(q0, c + 0);
        ISSUE(q0, CLMP(c + 8));  CHAIN(q1, c + 1);
        ISSUE(q1, CLMP(c + 9));  CHAIN(q2, c + 2);
        ISSUE(q2, CLMP(c + 10)); CHAIN(q3, c + 3);
        ISSUE(q3, CLMP(c + 11)); CHAIN(q4, c + 4);
        ISSUE(q4, CLMP(c + 12)); CHAIN(q5, c + 5);
        ISSUE(q5, CLMP(c + 13)); CHAIN(q6, c + 6);
        ISSUE(q6, CLMP(c + 14)); CHAIN(q7, c + 7);
    }

    // final h: q holds the last qang = psi_rev + 1/8
    float pr = qang - 0.125f;
    float hr = __builtin_amdgcn_cosf(pr);
    float hi = __builtin_amdgcn_sinf(pr);
    xf[b * 64 + d] = make_float2(hr, hi);

#undef ISSUE
#undef CHAIN
#undef CLMP
}

// ---------------------------------------------------------------------------
// Phase 2: the two resonant layers at t_last = (S-1)*phi.
// grid = B (64 blocks), block = N (128 threads).
// ---------------------------------------------------------------------------
__global__ __launch_bounds__(128) void layers_kernel(
    const float2* __restrict__ xf,       // [b][d]
    const float*  __restrict__ win_r,    // [L][D][N]
    const float*  __restrict__ win_i,
    const float*  __restrict__ wout_r,   // [L][N][D]
    const float*  __restrict__ wout_i,
    const float*  __restrict__ lw,       // [L][N]
    const float*  __restrict__ lb,
    float2*       __restrict__ xft)      // [d][b] for the projection kernel
{
    const int b = blockIdx.x;
    const int n = threadIdx.x;

    __shared__ float s_xr[D_SZ], s_xi[D_SZ];
    __shared__ float s_vr[N_SZ], s_vi[N_SZ];

    if (n < D_SZ) {
        float2 v = xf[b * D_SZ + n];
        s_xr[n] = v.x;
        s_xi[n] = v.y;
    }
    __syncthreads();

    const float t_last = (float)(4095.0 * 1.618033988749895);
    const float t_wrap = fmodf(t_last, TWO_PI_F);

    for (int l = 0; l < L_SZ; ++l) {
        float ur = 0.0f, ui = 0.0f;
        const float* wr = win_r + l * D_SZ * N_SZ;
        const float* wi = win_i + l * D_SZ * N_SZ;
        for (int dd = 0; dd < D_SZ; ++dd) {
            float xr = s_xr[dd], xi = s_xi[dd];
            float ar = wr[dd * N_SZ + n], ai = wi[dd * N_SZ + n];
            ur = fmaf(xr, ar, fmaf(-xi, ai, ur));
            ui = fmaf(xr, ai, fmaf( xi, ar, ui));
        }
        float lam = 1.0f + fabsf(lw[l * N_SZ + n]);
        float th  = t_wrap / lam + lb[l * N_SZ + n];
        float sn  = sinf(th), cs = cosf(th);
        float vr  = ur * cs - ui * sn;
        float vi  = ur * sn + ui * cs;
        vr = vr / (1.0f + expf(-vr));
        vi = vi / (1.0f + expf(-vi));
        s_vr[n] = vr;
        s_vi[n] = vi;
        __syncthreads();

        float yr = 0.0f, yi = 0.0f;
        if (n < D_SZ) {
            const float* orp = wout_r + l * N_SZ * D_SZ;
            const float* oip = wout_i + l * N_SZ * D_SZ;
            for (int j = 0; j < N_SZ; ++j) {
                float vr2 = s_vr[j], vi2 = s_vi[j];
                float br = orp[j * D_SZ + n], bi = oip[j * D_SZ + n];
                yr = fmaf(vr2, br, fmaf(-vi2, bi, yr));
                yi = fmaf(vr2, bi, fmaf( vi2, br, yi));
            }
        }
        __syncthreads();
        if (n < D_SZ) {
            s_xr[n] = yr;
            s_xi[n] = yi;
        }
        __syncthreads();
    }

    if (n < D_SZ) {
        xft[n * B_SZ + b] = make_float2(s_xr[n], s_xi[n]);
    }
}

// ---------------------------------------------------------------------------
// Phase 3: out[b][v] = xr[b]@(wr+wi)[:,v] + xi[b]@(wr-wi)[:,v].
// ---------------------------------------------------------------------------
#define VCH 16
__global__ __launch_bounds__(64) void proj_kernel(
    const float2* __restrict__ xft,    // [d][b]
    const float*  __restrict__ owr,    // [D][NSIG]
    const float*  __restrict__ owi,
    float*        __restrict__ out)    // [B][NSIG]
{
    const int v0   = blockIdx.x * VCH;
    const int lane = threadIdx.x;      // = b

    float acc[VCH];
    #pragma unroll
    for (int k = 0; k < VCH; ++k) acc[k] = 0.0f;

    for (int dd = 0; dd < D_SZ; ++dd) {
        float2 x = xft[dd * B_SZ + lane];
        #pragma unroll
        for (int k = 0; k < VCH; ++k) {
            float a = owr[dd * NSIG + v0 + k];
            float c = owi[dd * NSIG + v0 + k];
            acc[k] = fmaf(x.x, a + c, fmaf(x.y, a - c, acc[k]));
        }
    }

    float4* o4 = (float4*)(out + (size_t)lane * NSIG + v0);
    #pragma unroll
    for (int k = 0; k < VCH / 4; ++k) {
        o4[k] = make_float4(acc[4 * k], acc[4 * k + 1],
                            acc[4 * k + 2], acc[4 * k + 3]);
    }
}

// ---------------------------------------------------------------------------
extern "C" void kernel_launch(void* const* d_in, const int* in_sizes, int n_in,
                              void* d_out, int out_size, void* d_ws, size_t ws_size,
                              hipStream_t stream)
{
    const int*   ids    = (const int*)  d_in[0];
    const float* emb    = (const float*)d_in[1];
    const float* win_r  = (const float*)d_in[2];
    const float* win_i  = (const float*)d_in[3];
    const float* wout_r = (const float*)d_in[4];
    const float* wout_i = (const float*)d_in[5];
    const float* lw     = (const float*)d_in[6];
    const float* lb     = (const float*)d_in[7];
    const float* owr    = (const float*)d_in[8];
    const float* owi    = (const float*)d_in[9];
    float*       out    = (float*)d_out;

    float2* xf   = (float2*)d_ws;                        // 32 KB
    float2* xft  = (float2*)((char*)d_ws + 32 * 1024);   // 32 KB
    float2* embT = (float2*)((char*)d_ws + 64 * 1024);   // 16.4 MB

    const size_t need = 64 * 1024 + (size_t)NSIG * 64 * sizeof(float2);
    if (ws_size >= need) {
        transform_kernel<<<NSIG * 64 / 256, 256, 0, stream>>>(emb, embT);
        scan_kernel<true><<<B_SZ, 64, 0, stream>>>(ids, emb, embT, xf);
    } else {
        scan_kernel<false><<<B_SZ, 64, 0, stream>>>(ids, emb, (const float2*)emb, xf);
    }
    layers_kernel<<<B_SZ, 128, 0, stream>>>(xf, win_r, win_i, wout_r, wout_i,
                                            lw, lb, xft);
    proj_kernel<<<NSIG / VCH, 64, 0, stream>>>(xft, owr, owi, out);
}